// Round 5
// baseline (6281.195 us; speedup 1.0000x reference)
//
#include <hip/hip_runtime.h>

#define Bb 32
#define Tt 2048
#define Dd 256
#define Hh 256
#define G3 768  // 3*H

typedef _Float16 h2_t __attribute__((ext_vector_type(2)));
typedef _Float16 f16x8 __attribute__((ext_vector_type(8)));
typedef float f32x4 __attribute__((ext_vector_type(4)));
union H2U { unsigned u; _Float16 h[2]; h2_t v; };
union V16 { uint4 u; f16x8 f; };

__device__ __forceinline__ float fdot2f(unsigned a, unsigned b, float c) {
#if __has_builtin(__builtin_amdgcn_fdot2)
    H2U ua, ub; ua.u = a; ub.u = b;
    return __builtin_amdgcn_fdot2(ua.v, ub.v, c, false);
#else
    H2U ua, ub; ua.u = a; ub.u = b;
    return c + (float)ua.h[0] * (float)ub.h[0] + (float)ua.h[1] * (float)ub.h[1];
#endif
}

__device__ __forceinline__ float frcpf(float x) {
#if __has_builtin(__builtin_amdgcn_rcpf)
    return __builtin_amdgcn_rcpf(x);
#else
    return 1.0f / x;
#endif
}
__device__ __forceinline__ float sigmoidf_(float s) { return frcpf(1.0f + __expf(-s)); }
__device__ __forceinline__ float tanhf_(float u) {
    float e = __expf(2.0f * u);
    return 1.0f - 2.0f * frcpf(e + 1.0f);
}
// scalar-in/scalar-out DPP helpers (never pass arrays -- R2 lesson)
__device__ __forceinline__ float dpp_xor1(float v) {
    return __int_as_float(__builtin_amdgcn_update_dpp(0, __float_as_int(v), 0xB1, 0xF, 0xF, true));
}
__device__ __forceinline__ float dpp_xor2(float v) {
    return __int_as_float(__builtin_amdgcn_update_dpp(0, __float_as_int(v), 0x4E, 0xF, 0xF, true));
}

// ---------------------------------------------------------------------------
// k0: x fp32 -> f16 (into d_out scratch region)
// ---------------------------------------------------------------------------
__global__ void cvt_x_kernel(const float* __restrict__ x, _Float16* __restrict__ xo) {
    const size_t i = ((size_t)blockIdx.x * 256 + threadIdx.x) * 4;
    float4 v = *reinterpret_cast<const float4*>(x + i);
    H2U a, b;
    a.h[0] = (_Float16)v.x; a.h[1] = (_Float16)v.y;
    b.h[0] = (_Float16)v.z; b.h[1] = (_Float16)v.w;
    uint2 o; o.x = a.u; o.y = b.u;
    *reinterpret_cast<uint2*>(xo + i) = o;
}

// ---------------------------------------------------------------------------
// k1: WxT[n][k] f16 from Wx[k][n] fp32  (768 x 256)
// ---------------------------------------------------------------------------
__global__ void wxt_kernel(const float* __restrict__ Wx, _Float16* __restrict__ wxt) {
    const int o = blockIdx.x * 256 + threadIdx.x;  // o = n*128 + kp
    const int n = o >> 7, kp = o & 127;
    float f0 = Wx[(size_t)(2 * kp) * G3 + n];
    float f1 = Wx[(size_t)(2 * kp + 1) * G3 + n];
    H2U u; u.h[0] = (_Float16)f0; u.h[1] = (_Float16)f1;
    reinterpret_cast<unsigned*>(wxt)[o] = u.u;
}

// ---------------------------------------------------------------------------
// k2: xp = A(65536x256,f16) @ WxT^T + bias, f16 out. MFMA 16x16x32_f16.
// (unchanged -- ref-checked, k0..k2 combined ~80 us)
// ---------------------------------------------------------------------------
__global__ __launch_bounds__(256)
void gemm_xp_kernel(const _Float16* __restrict__ A, const _Float16* __restrict__ Bm,
                    const float* __restrict__ bias, _Float16* __restrict__ xp) {
    __shared__ _Float16 As[128][264];
    __shared__ _Float16 Bs[64][264];
    const int tid = threadIdx.x;
    const int m0 = (blockIdx.x / 12) * 128;
    const int n0 = (blockIdx.x % 12) * 64;

#pragma unroll
    for (int it = 0; it < 16; ++it) {
        int c = tid + it * 256, row = c >> 5, col = c & 31;
        uint4 v = *reinterpret_cast<const uint4*>(A + (size_t)(m0 + row) * 256 + col * 8);
        *reinterpret_cast<uint4*>(&As[row][col * 8]) = v;
    }
#pragma unroll
    for (int it = 0; it < 8; ++it) {
        int c = tid + it * 256, row = c >> 5, col = c & 31;
        uint4 v = *reinterpret_cast<const uint4*>(Bm + (size_t)(n0 + row) * 256 + col * 8);
        *reinterpret_cast<uint4*>(&Bs[row][col * 8]) = v;
    }
    __syncthreads();

    const int wave = tid >> 6, lane = tid & 63;
    const int wr = wave >> 1, wc = wave & 1;
    const int r16 = lane & 15, kg = lane >> 4;

    f32x4 acc[4][2];
#pragma unroll
    for (int mi = 0; mi < 4; ++mi)
#pragma unroll
        for (int ni = 0; ni < 2; ++ni) acc[mi][ni] = (f32x4){0.f, 0.f, 0.f, 0.f};

    float bv[2];
#pragma unroll
    for (int ni = 0; ni < 2; ++ni) bv[ni] = bias[n0 + wc * 32 + ni * 16 + r16];

#pragma unroll
    for (int kk = 0; kk < 8; ++kk) {
        f16x8 a[4], b2[2];
#pragma unroll
        for (int mi = 0; mi < 4; ++mi) {
            V16 t; t.u = *reinterpret_cast<const uint4*>(&As[wr * 64 + mi * 16 + r16][kk * 32 + kg * 8]);
            a[mi] = t.f;
        }
#pragma unroll
        for (int ni = 0; ni < 2; ++ni) {
            V16 t; t.u = *reinterpret_cast<const uint4*>(&Bs[wc * 32 + ni * 16 + r16][kk * 32 + kg * 8]);
            b2[ni] = t.f;
        }
#pragma unroll
        for (int mi = 0; mi < 4; ++mi)
#pragma unroll
            for (int ni = 0; ni < 2; ++ni)
                acc[mi][ni] = __builtin_amdgcn_mfma_f32_16x16x32_f16(a[mi], b2[ni], acc[mi][ni], 0, 0, 0);
    }

#pragma unroll
    for (int mi = 0; mi < 4; ++mi)
#pragma unroll
        for (int ni = 0; ni < 2; ++ni)
#pragma unroll
            for (int r = 0; r < 4; ++r) {
                int row = m0 + wr * 64 + mi * 16 + kg * 4 + r;
                int col = n0 + wc * 32 + ni * 16 + r16;
                xp[(size_t)row * G3 + col] = (_Float16)(acc[mi][ni][r] + bv[ni]);
            }
}

// ---------------------------------------------------------------------------
// k3: GRU scan, pure VALU dot2, ONE WAVE PER SIMD.
// R2/R4 failed because at >=2 waves/SIMD the 256-reg cap leaves no headroom
// for 192 weight regs + working set -> allocator parks weights in AGPR/scratch
// and pays a move per use (R4: VALU instrs ~2.5x expected). Fix: 256 threads
// (4 waves, 1/SIMD), weights = 384 u32/thread, cap = 512 VGPRs, and
// amdgpu_waves_per_eu(1,1) pins the allocator's occupancy target so it
// CANNOT trade registers for occupancy. Latency hiding via ILP only:
// 12 independent dot chains; x loads issued ~700 cyc before use; h reads
// as 8 up-front b128 broadcasts.
// Thread tid: q = tid&3 (k in [64q,64q+64)), slot = tid>>2; owns h-cols
// 4*slot..4*slot+3 for all 3 gates; its gate column is j == tid.
// Cross-q reduce: 2 DPP quad_perm stages. Barrier waits lgkmcnt only.
// ---------------------------------------------------------------------------
#define GDCOL(HU, KP)                                                                 \
    az0 = fdot2f(w[0][0][KP], HU, az0); ar0 = fdot2f(w[1][0][KP], HU, ar0);           \
    an0 = fdot2f(w[2][0][KP], HU, an0); az1 = fdot2f(w[0][1][KP], HU, az1);           \
    ar1 = fdot2f(w[1][1][KP], HU, ar1); an1 = fdot2f(w[2][1][KP], HU, an1);           \
    az2 = fdot2f(w[0][2][KP], HU, az2); ar2 = fdot2f(w[1][2][KP], HU, ar2);           \
    an2 = fdot2f(w[2][2][KP], HU, an2); az3 = fdot2f(w[0][3][KP], HU, az3);           \
    ar3 = fdot2f(w[1][3][KP], HU, ar3); an3 = fdot2f(w[2][3][KP], HU, an3);

#define GD4(I)                                                                        \
  {                                                                                   \
    uint4 hv = hq[I];                                                                 \
    GDCOL(hv.x, (I) * 4 + 0)                                                          \
    GDCOL(hv.y, (I) * 4 + 1)                                                          \
    GDCOL(hv.z, (I) * 4 + 2)                                                          \
    GDCOL(hv.w, (I) * 4 + 3)                                                          \
  }

#define GSTEP(PR, PW, T)                                                              \
  {                                                                                   \
    /* x-proj loads for THIS step, issued before the dot phase (~700 cyc) */          \
    const _Float16* xt = xq + (size_t)(T) * G3;                                       \
    const _Float16 xgz = xt[0], xgr = xt[Hh], xgn = xt[2 * Hh];                       \
    float az0 = 0.f, az1 = 0.f, az2 = 0.f, az3 = 0.f;                                 \
    float ar0 = 0.f, ar1 = 0.f, ar2 = 0.f, ar3 = 0.f;                                 \
    float an0 = 0.f, an1 = 0.f, an2 = 0.f, an3 = 0.f;                                 \
    const uint4* hq = reinterpret_cast<const uint4*>(&hbuf[PR][q * 36]);              \
    GD4(0) GD4(1) GD4(2) GD4(3) GD4(4) GD4(5) GD4(6) GD4(7)                           \
    az0 += dpp_xor1(az0); az1 += dpp_xor1(az1); az2 += dpp_xor1(az2);                 \
    az3 += dpp_xor1(az3); ar0 += dpp_xor1(ar0); ar1 += dpp_xor1(ar1);                 \
    ar2 += dpp_xor1(ar2); ar3 += dpp_xor1(ar3); an0 += dpp_xor1(an0);                 \
    an1 += dpp_xor1(an1); an2 += dpp_xor1(an2); an3 += dpp_xor1(an3);                 \
    az0 += dpp_xor2(az0); az1 += dpp_xor2(az1); az2 += dpp_xor2(az2);                 \
    az3 += dpp_xor2(az3); ar0 += dpp_xor2(ar0); ar1 += dpp_xor2(ar1);                 \
    ar2 += dpp_xor2(ar2); ar3 += dpp_xor2(ar3); an0 += dpp_xor2(an0);                 \
    an1 += dpp_xor2(an1); an2 += dpp_xor2(an2); an3 += dpp_xor2(an3);                 \
    /* this lane's gate column is c = q (j == tid) */                                 \
    const float hz = (q & 2) ? ((q & 1) ? az3 : az2) : ((q & 1) ? az1 : az0);         \
    const float hr = (q & 2) ? ((q & 1) ? ar3 : ar2) : ((q & 1) ? ar1 : ar0);         \
    const float hn = (q & 2) ? ((q & 1) ? an3 : an2) : ((q & 1) ? an1 : an0);         \
    const float zg = sigmoidf_((float)xgz + hz);                                      \
    const float rg = sigmoidf_((float)xgr + hr);                                      \
    const float ng = tanhf_((float)xgn + rg * hn);                                    \
    const float hnew = zg * hprev + (1.0f - zg) * ng;                                 \
    hprev = hnew;                                                                     \
    reinterpret_cast<_Float16*>(&hbuf[PW][0])[hoff] = (_Float16)hnew;                 \
    yb[(size_t)(T) * Hh] = hnew;                                                      \
    __builtin_amdgcn_sched_barrier(0);                                                \
    asm volatile("s_waitcnt lgkmcnt(0)" ::: "memory");                                \
    __builtin_amdgcn_s_barrier();                                                     \
    __builtin_amdgcn_sched_barrier(0);                                                \
  }

__global__ __launch_bounds__(256)
__attribute__((amdgpu_waves_per_eu(1, 1)))
void gru_scan_kernel(const _Float16* __restrict__ xp, const float* __restrict__ Wh,
                     float* __restrict__ y) {
    __shared__ unsigned hbuf[2][144];  // 4 chunks x (32 u32 + 4 pad): q-reads hit disjoint bank-quads

    const int tid = threadIdx.x;
    const int b = blockIdx.x;
    const int q = tid & 3;       // k quadrant: k in [64q, 64q+64)
    const int slot = tid >> 2;   // [0,64): owns h-cols 4*slot .. 4*slot+3

    // weights: [gate][c][32 k-pairs] f16x2-packed = 384 u32, all statically
    // indexed (full unroll), never passed by pointer.
    unsigned w[3][4][32];
#pragma unroll
    for (int g = 0; g < 3; ++g)
#pragma unroll
        for (int kp = 0; kp < 32; ++kp) {
            const int k = 64 * q + 2 * kp;
            const float* p0 = Wh + (size_t)k * G3 + g * Hh + 4 * slot;
            float4 va = *reinterpret_cast<const float4*>(p0);
            float4 vb = *reinterpret_cast<const float4*>(p0 + G3);
            H2U c0, c1, c2, c3;
            c0.h[0] = (_Float16)va.x; c0.h[1] = (_Float16)vb.x;
            c1.h[0] = (_Float16)va.y; c1.h[1] = (_Float16)vb.y;
            c2.h[0] = (_Float16)va.z; c2.h[1] = (_Float16)vb.z;
            c3.h[0] = (_Float16)va.w; c3.h[1] = (_Float16)vb.w;
            w[g][0][kp] = c0.u; w[g][1][kp] = c1.u;
            w[g][2][kp] = c2.u; w[g][3][kp] = c3.u;
        }

    for (int i = tid; i < 288; i += 256) hbuf[i / 144][i % 144] = 0u;  // h0 = 0
    float hprev = 0.0f;

    // this thread's gate column j == tid
    const int hoff = (tid >> 6) * 72 + (tid & 63);   // f16 index into padded hbuf row
    const _Float16* xq = xp + (size_t)b * Tt * G3 + tid;
    float* yb = y + (size_t)b * Tt * Hh + tid;

    __syncthreads();  // one-time full barrier (drains weight loads too)

#pragma unroll 1
    for (int t = 0; t < Tt; t += 2) {
        GSTEP(0, 1, t);
        GSTEP(1, 0, t + 1);
    }
}

extern "C" void kernel_launch(void* const* d_in, const int* in_sizes, int n_in,
                              void* d_out, int out_size, void* d_ws, size_t ws_size,
                              hipStream_t stream) {
    (void)in_sizes; (void)n_in; (void)out_size; (void)ws_size;
    const float* x    = (const float*)d_in[0];
    const float* Wx   = (const float*)d_in[1];
    const float* Wh   = (const float*)d_in[2];
    const float* bias = (const float*)d_in[3];
    float* y = (float*)d_out;

    _Float16* xp   = (_Float16*)d_ws;                                // 96 MB
    _Float16* xf16 = (_Float16*)d_out;                               // 33.5 MB scratch in d_out
    _Float16* wxt  = (_Float16*)((char*)d_out + (size_t)33554432);   // 384 KB, after xf16

    cvt_x_kernel<<<dim3(16384), dim3(256), 0, stream>>>(x, xf16);
    wxt_kernel<<<dim3(384), dim3(256), 0, stream>>>(Wx, wxt);
    gemm_xp_kernel<<<dim3(6144), dim3(256), 0, stream>>>(xf16, wxt, bias, xp);
    // scan reads only ws, writes all of d_out (overwriting the scratch regions)
    gru_scan_kernel<<<dim3(Bb), dim3(256), 0, stream>>>(xp, Wh, y);
}

// Round 6
// 2297.060 us; speedup vs baseline: 2.7344x; 2.7344x over previous
//
#include <hip/hip_runtime.h>

#define Bb 32
#define Tt 2048
#define Dd 256
#define Hh 256
#define G3 768  // 3*H

typedef _Float16 h2_t __attribute__((ext_vector_type(2)));
typedef _Float16 f16x8 __attribute__((ext_vector_type(8)));
typedef float f32x4 __attribute__((ext_vector_type(4)));
union H2U { unsigned u; _Float16 h[2]; h2_t v; };
union V16 { uint4 u; f16x8 f; };

__device__ __forceinline__ float fdot2f(unsigned a, unsigned b, float c) {
#if __has_builtin(__builtin_amdgcn_fdot2)
    H2U ua, ub; ua.u = a; ub.u = b;
    return __builtin_amdgcn_fdot2(ua.v, ub.v, c, false);
#else
    H2U ua, ub; ua.u = a; ub.u = b;
    return c + (float)ua.h[0] * (float)ub.h[0] + (float)ua.h[1] * (float)ub.h[1];
#endif
}

__device__ __forceinline__ float frcpf(float x) {
#if __has_builtin(__builtin_amdgcn_rcpf)
    return __builtin_amdgcn_rcpf(x);
#else
    return 1.0f / x;
#endif
}
__device__ __forceinline__ float sigmoidf_(float s) { return frcpf(1.0f + __expf(-s)); }
__device__ __forceinline__ float tanhf_(float u) {
    float e = __expf(2.0f * u);
    return 1.0f - 2.0f * frcpf(e + 1.0f);
}
// scalar-in/scalar-out DPP helpers (never pass arrays -- R2 lesson)
__device__ __forceinline__ float dpp_xor1(float v) {
    return __int_as_float(__builtin_amdgcn_update_dpp(0, __float_as_int(v), 0xB1, 0xF, 0xF, true));
}
__device__ __forceinline__ float dpp_xor2(float v) {
    return __int_as_float(__builtin_amdgcn_update_dpp(0, __float_as_int(v), 0x4E, 0xF, 0xF, true));
}

// ---------------------------------------------------------------------------
// k0: x fp32 -> f16 (into d_out scratch region)
// ---------------------------------------------------------------------------
__global__ void cvt_x_kernel(const float* __restrict__ x, _Float16* __restrict__ xo) {
    const size_t i = ((size_t)blockIdx.x * 256 + threadIdx.x) * 4;
    float4 v = *reinterpret_cast<const float4*>(x + i);
    H2U a, b;
    a.h[0] = (_Float16)v.x; a.h[1] = (_Float16)v.y;
    b.h[0] = (_Float16)v.z; b.h[1] = (_Float16)v.w;
    uint2 o; o.x = a.u; o.y = b.u;
    *reinterpret_cast<uint2*>(xo + i) = o;
}

// ---------------------------------------------------------------------------
// k1: WxT[n][k] f16 from Wx[k][n] fp32  (768 x 256)
// ---------------------------------------------------------------------------
__global__ void wxt_kernel(const float* __restrict__ Wx, _Float16* __restrict__ wxt) {
    const int o = blockIdx.x * 256 + threadIdx.x;  // o = n*128 + kp
    const int n = o >> 7, kp = o & 127;
    float f0 = Wx[(size_t)(2 * kp) * G3 + n];
    float f1 = Wx[(size_t)(2 * kp + 1) * G3 + n];
    H2U u; u.h[0] = (_Float16)f0; u.h[1] = (_Float16)f1;
    reinterpret_cast<unsigned*>(wxt)[o] = u.u;
}

// ---------------------------------------------------------------------------
// k2: xp = A(65536x256,f16) @ WxT^T + bias, f16 out. MFMA 16x16x32_f16.
// (unchanged -- ref-checked)
// ---------------------------------------------------------------------------
__global__ __launch_bounds__(256)
void gemm_xp_kernel(const _Float16* __restrict__ A, const _Float16* __restrict__ Bm,
                    const float* __restrict__ bias, _Float16* __restrict__ xp) {
    __shared__ _Float16 As[128][264];
    __shared__ _Float16 Bs[64][264];
    const int tid = threadIdx.x;
    const int m0 = (blockIdx.x / 12) * 128;
    const int n0 = (blockIdx.x % 12) * 64;

#pragma unroll
    for (int it = 0; it < 16; ++it) {
        int c = tid + it * 256, row = c >> 5, col = c & 31;
        uint4 v = *reinterpret_cast<const uint4*>(A + (size_t)(m0 + row) * 256 + col * 8);
        *reinterpret_cast<uint4*>(&As[row][col * 8]) = v;
    }
#pragma unroll
    for (int it = 0; it < 8; ++it) {
        int c = tid + it * 256, row = c >> 5, col = c & 31;
        uint4 v = *reinterpret_cast<const uint4*>(Bm + (size_t)(n0 + row) * 256 + col * 8);
        *reinterpret_cast<uint4*>(&Bs[row][col * 8]) = v;
    }
    __syncthreads();

    const int wave = tid >> 6, lane = tid & 63;
    const int wr = wave >> 1, wc = wave & 1;
    const int r16 = lane & 15, kg = lane >> 4;

    f32x4 acc[4][2];
#pragma unroll
    for (int mi = 0; mi < 4; ++mi)
#pragma unroll
        for (int ni = 0; ni < 2; ++ni) acc[mi][ni] = (f32x4){0.f, 0.f, 0.f, 0.f};

    float bv[2];
#pragma unroll
    for (int ni = 0; ni < 2; ++ni) bv[ni] = bias[n0 + wc * 32 + ni * 16 + r16];

#pragma unroll
    for (int kk = 0; kk < 8; ++kk) {
        f16x8 a[4], b2[2];
#pragma unroll
        for (int mi = 0; mi < 4; ++mi) {
            V16 t; t.u = *reinterpret_cast<const uint4*>(&As[wr * 64 + mi * 16 + r16][kk * 32 + kg * 8]);
            a[mi] = t.f;
        }
#pragma unroll
        for (int ni = 0; ni < 2; ++ni) {
            V16 t; t.u = *reinterpret_cast<const uint4*>(&Bs[wc * 32 + ni * 16 + r16][kk * 32 + kg * 8]);
            b2[ni] = t.f;
        }
#pragma unroll
        for (int mi = 0; mi < 4; ++mi)
#pragma unroll
            for (int ni = 0; ni < 2; ++ni)
                acc[mi][ni] = __builtin_amdgcn_mfma_f32_16x16x32_f16(a[mi], b2[ni], acc[mi][ni], 0, 0, 0);
    }

#pragma unroll
    for (int mi = 0; mi < 4; ++mi)
#pragma unroll
        for (int ni = 0; ni < 2; ++ni)
#pragma unroll
            for (int r = 0; r < 4; ++r) {
                int row = m0 + wr * 64 + mi * 16 + kg * 4 + r;
                int col = n0 + wc * 32 + ni * 16 + r16;
                xp[(size_t)row * G3 + col] = (_Float16)(acc[mi][ni][r] + bv[ni]);
            }
}

// ---------------------------------------------------------------------------
// k3: GRU scan, pure VALU dot2. 32 blocks x 512 threads (8 waves, 2/SIMD).
// KEY LESSON (R5): 256 VGPRs is the HARD addressable cap for VALU code
// (v0..v255; the "512" unified file is VGPR+AGPR and v_dot2 can't read
// AGPRs). So per-thread weights must be < ~190 u32 => 512 threads.
// KEY LESSON (R4): __launch_bounds__(512,2) pins only MIN waves/EU; the
// allocator targeted 4 waves/EU (128 regs) and AGPR-parked the weights
// (2.5x VALU inflation). Fix: amdgpu_waves_per_eu(2,2) pins MAX too ->
// budget exactly 256.
// Margin: only k-pairs 0..27 per (gate,col) in VGPRs (168 u32); k-pairs
// 28..31 streamed per step from LDS (49 KB, wave-linear layout, 6 x
// ds_read_b128/thread, conflict-free; ~400 cyc on ds pipe, overlapped with
// the 768-cyc VALU dot phase). An asm-laundered offset defeats LICM so the
// streamed weights are NOT hoisted into registers.
// Thread (q=tid&3, slot=tid>>2): owns h-cols {2slot, 2slot+1} x 3 gates,
// k in [64q, 64q+64). Cross-q reduce = 2 DPP quad_perm stages.
// Barrier waits lgkmcnt only (y-stores / xp prefetch stay in flight).
// ---------------------------------------------------------------------------
#define GDCOL2(HU, KP)                                                                \
    az0 = fdot2f(w[0][0][KP], HU, az0); ar0 = fdot2f(w[1][0][KP], HU, ar0);           \
    an0 = fdot2f(w[2][0][KP], HU, an0); az1 = fdot2f(w[0][1][KP], HU, az1);           \
    ar1 = fdot2f(w[1][1][KP], HU, ar1); an1 = fdot2f(w[2][1][KP], HU, an1);

#define GD4R(I)                                                                       \
  {                                                                                   \
    uint4 hv = hq[I];                                                                 \
    GDCOL2(hv.x, (I) * 4 + 0)                                                         \
    GDCOL2(hv.y, (I) * 4 + 1)                                                         \
    GDCOL2(hv.z, (I) * 4 + 2)                                                         \
    GDCOL2(hv.w, (I) * 4 + 3)                                                         \
  }

#define GSW4(ACC, SW, HV)                                                             \
    ACC = fdot2f(SW.x, HV.x, ACC); ACC = fdot2f(SW.y, HV.y, ACC);                     \
    ACC = fdot2f(SW.z, HV.z, ACC); ACC = fdot2f(SW.w, HV.w, ACC);

#define GSTEP(PR, PW, T)                                                              \
  {                                                                                   \
    /* prefetch next step's x-proj triple (consumed next iteration) */                \
    const _Float16* xnp = xq + (size_t)((T) + 1 < Tt ? (T) + 1 : (T)) * G3;           \
    _Float16 pz = xnp[0], pr = xnp[Hh], pn = xnp[2 * Hh];                             \
    /* streamed weights: laundered offset defeats LICM (must stay in-loop) */         \
    unsigned off = 0;                                                                 \
    asm volatile("" : "+v"(off));                                                     \
    const uint4* swp = wlds4 + (wave * 6) * 64 + lane + off;                          \
    uint4 sw00 = swp[0];                                                              \
    uint4 sw01 = swp[64];                                                             \
    uint4 sw10 = swp[128];                                                            \
    uint4 sw11 = swp[192];                                                            \
    uint4 sw20 = swp[256];                                                            \
    uint4 sw21 = swp[320];                                                            \
    float az0 = 0.f, az1 = 0.f, ar0 = 0.f, ar1 = 0.f, an0 = 0.f, an1 = 0.f;           \
    const uint4* hq = reinterpret_cast<const uint4*>(&hbuf[PR][q * 36]);              \
    GD4R(0) GD4R(1) GD4R(2) GD4R(3) GD4R(4) GD4R(5) GD4R(6)                           \
    {                                                                                 \
      uint4 hv = hq[7];                                                               \
      GSW4(az0, sw00, hv) GSW4(az1, sw01, hv)                                         \
      GSW4(ar0, sw10, hv) GSW4(ar1, sw11, hv)                                         \
      GSW4(an0, sw20, hv) GSW4(an1, sw21, hv)                                         \
    }                                                                                 \
    /* quad butterfly: all 4 q-lanes end with full-k sums */                          \
    az0 += dpp_xor1(az0); az1 += dpp_xor1(az1);                                       \
    ar0 += dpp_xor1(ar0); ar1 += dpp_xor1(ar1);                                       \
    an0 += dpp_xor1(an0); an1 += dpp_xor1(an1);                                       \
    az0 += dpp_xor2(az0); az1 += dpp_xor2(az1);                                       \
    ar0 += dpp_xor2(ar0); ar1 += dpp_xor2(ar1);                                       \
    an0 += dpp_xor2(an0); an1 += dpp_xor2(an1);                                       \
    const float hz = (q & 1) ? az1 : az0;                                             \
    const float hr = (q & 1) ? ar1 : ar0;                                             \
    const float hn = (q & 1) ? an1 : an0;                                             \
    const float zg = sigmoidf_(xz + hz);                                              \
    const float rg = sigmoidf_(xr + hr);                                              \
    const float ng = tanhf_(xn + rg * hn);                                            \
    const float hnew = zg * hprev + (1.0f - zg) * ng;                                 \
    hprev = hnew;                                                                     \
    H2U hc; hc.h[0] = (_Float16)hnew; hc.h[1] = (_Float16)0.f;                        \
    const unsigned pu = (unsigned)__builtin_amdgcn_update_dpp(0, (int)hc.u, 0xB1, 0xF, 0xF, true); \
    const int pf = __builtin_amdgcn_update_dpp(0, __float_as_int(hnew), 0xB1, 0xF, 0xF, true);      \
    if (q == 0) {                                                                     \
      hbuf[PW][(slot >> 5) * 36 + (slot & 31)] = (hc.u & 0xFFFFu) | (pu << 16);       \
      float2 yv; yv.x = hnew; yv.y = __int_as_float(pf);                              \
      *reinterpret_cast<float2*>(yb + (size_t)(T) * Hh) = yv;                         \
    }                                                                                 \
    xz = (float)pz; xr = (float)pr; xn = (float)pn;                                   \
    __builtin_amdgcn_sched_barrier(0);                                                \
    asm volatile("s_waitcnt lgkmcnt(0)" ::: "memory");                                \
    __builtin_amdgcn_s_barrier();                                                     \
    __builtin_amdgcn_sched_barrier(0);                                                \
  }

__global__ __launch_bounds__(512)
__attribute__((amdgpu_waves_per_eu(2, 2)))
void gru_scan_kernel(const _Float16* __restrict__ xp, const float* __restrict__ Wh,
                     float* __restrict__ y) {
    __shared__ uint4 wlds4[8 * 6 * 64];   // 49152 B: [wave][gc][lane], wave-linear
    __shared__ unsigned hbuf[2][144];     // 4 chunks x (32 u32 + 4 pad): conflict-free

    const int tid = threadIdx.x;
    const int b = blockIdx.x;
    const int q = tid & 3;       // k quadrant: k in [64q, 64q+64)
    const int slot = tid >> 2;   // [0,128): owns h-cols 2*slot, 2*slot+1
    const int wave = tid >> 6, lane = tid & 63;

    // weights k-pairs 0..27 -> VGPRs (168 u32), all statically indexed
    unsigned w[3][2][28];
#pragma unroll
    for (int g = 0; g < 3; ++g) {
        const int c0 = g * Hh + 2 * slot;
#pragma unroll
        for (int kp = 0; kp < 28; ++kp) {
            const int k = 64 * q + 2 * kp;
            float2 f0 = *reinterpret_cast<const float2*>(Wh + (size_t)k * G3 + c0);
            float2 f1 = *reinterpret_cast<const float2*>(Wh + (size_t)(k + 1) * G3 + c0);
            H2U p0, p1;
            p0.h[0] = (_Float16)f0.x; p0.h[1] = (_Float16)f1.x;
            p1.h[0] = (_Float16)f0.y; p1.h[1] = (_Float16)f1.y;
            w[g][0][kp] = p0.u;
            w[g][1][kp] = p1.u;
        }
        // weights k-pairs 28..31 -> LDS (streamed each step)
        unsigned a0, a1, a2, a3, b0, b1, b2, b3;
#pragma unroll
        for (int e = 0; e < 4; ++e) {
            const int k = 64 * q + 2 * (28 + e);
            float2 f0 = *reinterpret_cast<const float2*>(Wh + (size_t)k * G3 + c0);
            float2 f1 = *reinterpret_cast<const float2*>(Wh + (size_t)(k + 1) * G3 + c0);
            H2U p0, p1;
            p0.h[0] = (_Float16)f0.x; p0.h[1] = (_Float16)f1.x;
            p1.h[0] = (_Float16)f0.y; p1.h[1] = (_Float16)f1.y;
            if (e == 0)      { a0 = p0.u; b0 = p1.u; }
            else if (e == 1) { a1 = p0.u; b1 = p1.u; }
            else if (e == 2) { a2 = p0.u; b2 = p1.u; }
            else             { a3 = p0.u; b3 = p1.u; }
        }
        uint4 sA; sA.x = a0; sA.y = a1; sA.z = a2; sA.w = a3;
        uint4 sB; sB.x = b0; sB.y = b1; sB.z = b2; sB.w = b3;
        wlds4[(wave * 6 + g * 2 + 0) * 64 + lane] = sA;
        wlds4[(wave * 6 + g * 2 + 1) * 64 + lane] = sB;
    }

    if (tid < 288) hbuf[tid / 144][tid % 144] = 0u;  // h0 = 0 (both buffers)
    float hprev = 0.0f;

    const int j = 2 * slot + (q & 1);  // this lane's gate column
    const _Float16* xq = xp + (size_t)b * Tt * G3 + j;
    float* yb = y + (size_t)b * Tt * Hh + 2 * slot;  // float2 store by q==0
    float xz = (float)xq[0], xr = (float)xq[Hh], xn = (float)xq[2 * Hh];

    __syncthreads();  // one-time full barrier (drains weight loads/stores)

#pragma unroll 1
    for (int t = 0; t < Tt; t += 2) {
        GSTEP(0, 1, t);
        GSTEP(1, 0, t + 1);
    }
}

extern "C" void kernel_launch(void* const* d_in, const int* in_sizes, int n_in,
                              void* d_out, int out_size, void* d_ws, size_t ws_size,
                              hipStream_t stream) {
    (void)in_sizes; (void)n_in; (void)out_size; (void)ws_size;
    const float* x    = (const float*)d_in[0];
    const float* Wx   = (const float*)d_in[1];
    const float* Wh   = (const float*)d_in[2];
    const float* bias = (const float*)d_in[3];
    float* y = (float*)d_out;

    _Float16* xp   = (_Float16*)d_ws;                                // 96 MB
    _Float16* xf16 = (_Float16*)d_out;                               // 33.5 MB scratch in d_out
    _Float16* wxt  = (_Float16*)((char*)d_out + (size_t)33554432);   // 384 KB, after xf16

    cvt_x_kernel<<<dim3(16384), dim3(256), 0, stream>>>(x, xf16);
    wxt_kernel<<<dim3(384), dim3(256), 0, stream>>>(Wx, wxt);
    gemm_xp_kernel<<<dim3(6144), dim3(256), 0, stream>>>(xf16, wxt, bias, xp);
    // scan reads only ws, writes all of d_out (overwriting the scratch regions)
    gru_scan_kernel<<<dim3(Bb), dim3(512), 0, stream>>>(xp, Wh, y);
}